// Round 20
// baseline (92.989 us; speedup 1.0000x reference)
//
#include <hip/hip_runtime.h>
#include <hip/hip_fp16.h>
#include <cstdint>

#define BB 2
#define SS 512
#define EE 256
#define NN (BB*SS)           // 1024 rows
#define KTOT (EE*EE)         // 65536
#define SPLITK 32
#define KCHUNK (KTOT/SPLITK) // 2048
#define NSTEP 64             // 64 k-steps per chunk
#define TSTEPS (KTOT/32)     // 2048 packed 32-k blocks
#define LN_EPS 1e-3f

typedef _Float16 f16;
typedef _Float16 f16x8 __attribute__((ext_vector_type(8)));
typedef float    f32x4 __attribute__((ext_vector_type(4)));

#define NPACK 512            // pack blocks: 4 cgroups x 128 kgroups

// ---------------- Kernel 1: FUSED pack (LDS transpose) + full wprefix.
// Blocks [0, NPACK): pack cm f32 -> cmP f16, coalesced both sides.
// Blocks [NPACK, NPACK+32): wprefix, one block per (b, eh, it); loops its
// j-tiles accumulating IN REGISTERS, writes s (sbuf) directly — no ps, no
// reduce_s kernel.
__global__ void prep_kernel(const float* __restrict__ cm, f16* __restrict__ cmP,
                            const float* __restrict__ x, float* __restrict__ s) {
    __shared__ __align__(16) char smem[35072];
    const int bid = blockIdx.x;
    const int tid = threadIdx.x;
    const int wave = tid >> 6;
    const int lane = tid & 63;

    if (bid < NPACK) {
        const int cg = bid >> 7;          // 0..3
        const int kg = bid & 127;         // 0..127
        f16* lt = (f16*)smem;             // [64 slots][264] (pad 8)
        #pragma unroll
        for (int h = 0; h < 2; ++h) {
            #pragma unroll
            for (int i = 0; i < 8; ++i) {
                const int rl = i * 4 + wave;                   // 0..31
                const int row = cg * 64 + h * 32 + rl;
                const float* src = cm + (size_t)row * KTOT + kg * 512 + lane * 8;
                float4 lo = *(const float4*)(src);
                float4 hi = *(const float4*)(src + 4);
                f16x8 v = { (f16)lo.x, (f16)lo.y, (f16)lo.z, (f16)lo.w,
                            (f16)hi.x, (f16)hi.y, (f16)hi.z, (f16)hi.w };
                *(f16x8*)(lt + lane * 264 + rl * 8) = v;
            }
            __syncthreads();
            #pragma unroll
            for (int jj = 0; jj < 8; ++jj) {
                const int sl = jj * 8 + wave * 2 + (lane >> 5);  // slot 0..63
                const int cl = lane & 31;
                f16x8 v = *(const f16x8*)(lt + sl * 264 + cl * 8);
                const int t    = kg * 16 + (sl >> 2);
                const int koct = sl & 3;
                const int c    = cg * 64 + h * 32 + cl;
                *(f16x8*)(cmP + (size_t)t * 8192 + koct * 2048 + c * 8) = v;
            }
            __syncthreads();
        }
        return;
    }

    // ---- wprefix (register-accumulating over j-tiles)
    float (*xt)[128] = (float(*)[128])smem;            // 64 x 128 f32
    float* wl2 = (float*)(smem + 32768);               // 576 f32
    const int id = bid - NPACK;            // 0..31
    const int eh = id & 1;
    const int b  = (id >> 1) & 1;
    const int it = id >> 2;                // 0..7
    const int ibase = it * 64;

    for (int t = tid; t < 576; t += 256) {
        const int d = t - 64;
        wl2[t] = (d > 0) ? 1.0f / ((float)d * (float)d) : 0.0f;
    }

    const int g  = tid >> 5;
    const int ec = (tid & 31) * 4;
    const int irow = ibase + g * 8;
    float4 acc[8];
    #pragma unroll
    for (int m = 0; m < 8; ++m) acc[m] = (float4){0.f, 0.f, 0.f, 0.f};

    for (int jt = 0; jt <= it; ++jt) {
        const int jbase = jt * 64;
        __syncthreads();
        const float* xb = x + ((size_t)b * SS + jbase) * EE + eh * 128;
        #pragma unroll
        for (int p = 0; p < 8; ++p) {
            const int row = p * 8 + (tid >> 5);
            const int col = (tid & 31) * 4;
            *(float4*)&xt[row][col] = *(const float4*)(xb + (size_t)row * EE + col);
        }
        __syncthreads();
        for (int jj = 0; jj < 64; ++jj) {
            const float4 xv = *(const float4*)&xt[jj][ec];
            const int wbase = irow - (jbase + jj) + 64;
            #pragma unroll
            for (int m = 0; m < 8; ++m) {
                const float w = wl2[wbase + m];
                acc[m].x += xv.x * w;
                acc[m].y += xv.y * w;
                acc[m].z += xv.z * w;
                acc[m].w += xv.w * w;
            }
        }
    }

    float* base = s + ((size_t)b * SS + ibase) * EE + eh * 128;
    #pragma unroll
    for (int m = 0; m < 8; ++m)
        *(float4*)(base + (size_t)(g * 8 + m) * EE + ec) = acc[m];
}

// ---------------- Kernel 2: split-K MFMA GEMM — reg-direct B (R17 structure,
// SPLITK=32, 512 blocks). A/B change this round: NO sched_barriers — let the
// compiler software-pipeline across steps (buffer WAR deps cap hoist depth).
__launch_bounds__(256, 2)
__global__ void gemm_kernel(const float* __restrict__ x,
                            const float* __restrict__ sbuf,
                            const f16* __restrict__ cmP,
                            f16* __restrict__ part) {
    __shared__ __align__(16) f16 Ep[64 * 264];   // epilogue stage, 33.8 KB
    const int tid  = threadIdx.x;
    const int lane = tid & 63;
    const int wave = tid >> 6;       // col-quarter 0..3
    const int koct = lane >> 4;      // k-octet 0..3
    const int cl   = lane & 15;

    const int d = blockIdx.x;            // 0..511
    const int nblock = (d >> 3) & 15;
    const int chunk  = (d & 7) * 4 + (d >> 7);   // XCD-grouped chunks

    // ---- xf loads (8 global loads)
    f16x8 xf[4];
    #pragma unroll
    for (int rt = 0; rt < 4; ++rt) {
        const int r = nblock * 64 + rt * 16 + cl;
        const float* xr = x + (size_t)r * EE + chunk * 8;
        float4 xlo = *(const float4*)(xr);
        float4 xhi = *(const float4*)(xr + 4);
        xf[rt] = (f16x8){ (f16)xlo.x, (f16)xlo.y, (f16)xlo.z, (f16)xlo.w,
                          (f16)xhi.x, (f16)xhi.y, (f16)xhi.z, (f16)xhi.w };
    }
    // ---- svm m=0 loads (8 global loads)
    float4 p0[4][2];
    #pragma unroll
    for (int rt = 0; rt < 4; ++rt) {
        const int r = nblock * 64 + rt * 16 + cl;
        const float* sr = sbuf + (size_t)r * EE + koct * 8;
        p0[rt][0] = *(const float4*)(sr);
        p0[rt][1] = *(const float4*)(sr + 4);
    }

    // per-lane B base: chunk slice + koct slot + wave slice + col-low
    const char* bbase = (const char*)cmP + (size_t)chunk * (64 * 16384)
                      + koct * 4096 + wave * 1024 + cl * 16;
    // step v covers packed block t = ((v&7)<<3)|(v>>3)
    #define TOFF(v) ((size_t)((((v) & 7) << 3) | ((v) >> 3)) * 16384)
    #define LOADB(BUF, v) do {                                              \
        _Pragma("unroll")                                                   \
        for (int ct_ = 0; ct_ < 4; ++ct_)                                   \
            BUF[ct_] = *(const f16x8*)(bbase + TOFF(v) + ct_ * 256);        \
    } while (0)

    f16x8 b0[4], b1[4], b2[4], b3[4];
    LOADB(b0, 0); LOADB(b1, 1); LOADB(b2, 2);

    f32x4 acc[4][4];
    #pragma unroll
    for (int a = 0; a < 4; ++a)
        #pragma unroll
        for (int b = 0; b < 4; ++b) acc[a][b] = (f32x4){0.f, 0.f, 0.f, 0.f};

    f16x8 svm[4];
    #pragma unroll
    for (int rt = 0; rt < 4; ++rt)
        svm[rt] = (f16x8){ (f16)p0[rt][0].x, (f16)p0[rt][0].y,
                           (f16)p0[rt][0].z, (f16)p0[rt][0].w,
                           (f16)p0[rt][1].x, (f16)p0[rt][1].y,
                           (f16)p0[rt][1].z, (f16)p0[rt][1].w };

    float4 pnxt[4][2];

    // One step: uses buffer BU (holds B(v)), loads B(v+3) into BL.
    #define STEP(mm, aa, BU, BL) do {                                       \
        const int v_ = (mm) * 8 + (aa);                                     \
        if ((aa) == 6 && (mm) < 7) {                                        \
            _Pragma("unroll")                                               \
            for (int rt_ = 0; rt_ < 4; ++rt_) {                             \
                const int r_ = nblock * 64 + rt_ * 16 + cl;                 \
                const float* sr_ = sbuf + (size_t)r_ * EE + ((mm) + 1) * 32 \
                                 + koct * 8;                                \
                pnxt[rt_][0] = *(const float4*)(sr_);                       \
                pnxt[rt_][1] = *(const float4*)(sr_ + 4);                   \
            }                                                               \
        }                                                                   \
        f16x8 af_[4];                                                       \
        _Pragma("unroll")                                                   \
        for (int rt_ = 0; rt_ < 4; ++rt_) {                                 \
            const f16 xa_ = xf[rt_][(aa)];                                  \
            const f16x8 xa8_ = { xa_, xa_, xa_, xa_, xa_, xa_, xa_, xa_ };  \
            af_[rt_] = xa8_ * svm[rt_];                                     \
        }                                                                   \
        __builtin_amdgcn_s_setprio(1);                                      \
        _Pragma("unroll")                                                   \
        for (int ct_ = 0; ct_ < 4; ++ct_)                                   \
            _Pragma("unroll")                                               \
            for (int rt_ = 0; rt_ < 4; ++rt_)                               \
                acc[rt_][ct_] = __builtin_amdgcn_mfma_f32_16x16x32_f16(     \
                    af_[rt_], BU[ct_], acc[rt_][ct_], 0, 0, 0);             \
        __builtin_amdgcn_s_setprio(0);                                      \
        if (v_ + 3 < NSTEP) LOADB(BL, v_ + 3);                              \
        if ((aa) == 7 && (mm) < 7) {                                        \
            _Pragma("unroll")                                               \
            for (int rt_ = 0; rt_ < 4; ++rt_)                               \
                svm[rt_] = (f16x8){                                         \
                    (f16)pnxt[rt_][0].x, (f16)pnxt[rt_][0].y,               \
                    (f16)pnxt[rt_][0].z, (f16)pnxt[rt_][0].w,               \
                    (f16)pnxt[rt_][1].x, (f16)pnxt[rt_][1].y,               \
                    (f16)pnxt[rt_][1].z, (f16)pnxt[rt_][1].w };             \
        }                                                                   \
    } while (0)

    #pragma unroll
    for (int m = 0; m < 8; ++m) {
        STEP(m, 0, b0, b3);
        STEP(m, 1, b1, b0);
        STEP(m, 2, b2, b1);
        STEP(m, 3, b3, b2);
        STEP(m, 4, b0, b3);
        STEP(m, 5, b1, b0);
        STEP(m, 6, b2, b1);
        STEP(m, 7, b3, b2);
    }
    #undef STEP
    #undef LOADB
    #undef TOFF

    // ---- Epilogue: f16 via padded LDS stage, then contiguous row stores.
    __syncthreads();
    #pragma unroll
    for (int rt = 0; rt < 4; ++rt) {
        #pragma unroll
        for (int ct = 0; ct < 4; ++ct) {
            const int col = wave * 64 + ct * 16 + cl;
            #pragma unroll
            for (int q = 0; q < 4; ++q) {
                const int lr = rt * 16 + koct * 4 + q;
                Ep[lr * 264 + col] = (f16)acc[rt][ct][q];
            }
        }
    }
    __syncthreads();
    {
        const int lr  = tid >> 2;         // 0..63
        const int seg = tid & 3;          // 0..3 (64 cols each)
        f16* dst = part + ((size_t)chunk * NN + nblock * 64 + lr) * EE + seg * 64;
        const f16* srcE = Ep + lr * 264 + seg * 64;
        #pragma unroll
        for (int i = 0; i < 8; ++i)
            *(f16x8*)(dst + i * 8) = *(const f16x8*)(srcE + i * 8);
    }
}

// ---------------- Kernel 3: split-K reduce + residual + LayerNorm (f16 partials)
__global__ void reduce_ln_kernel(const float* __restrict__ x,
                                 const f16* __restrict__ part,
                                 const float* __restrict__ gamma,
                                 const float* __restrict__ beta,
                                 float* __restrict__ out) {
    const int n = blockIdx.x;
    const int c = threadIdx.x;
    const int lane = c & 63, wave = c >> 6;
    float y = x[(size_t)n * EE + c];
    #pragma unroll 8
    for (int ch = 0; ch < SPLITK; ++ch)
        y += (float)part[((size_t)ch * NN + n) * EE + c];

    float v = y;
    #pragma unroll
    for (int o = 32; o > 0; o >>= 1) v += __shfl_xor(v, o);
    __shared__ float red[8];
    if (lane == 0) red[wave] = v;
    __syncthreads();
    const float mean = (red[0] + red[1] + red[2] + red[3]) * (1.0f / EE);
    const float d = y - mean;
    float sq = d * d;
    #pragma unroll
    for (int o = 32; o > 0; o >>= 1) sq += __shfl_xor(sq, o);
    if (lane == 0) red[4 + wave] = sq;
    __syncthreads();
    const float var = (red[4] + red[5] + red[6] + red[7]) * (1.0f / EE);
    out[(size_t)n * EE + c] = d * rsqrtf(var + LN_EPS) * gamma[c] + beta[c];
}

extern "C" void kernel_launch(void* const* d_in, const int* in_sizes, int n_in,
                              void* d_out, int out_size, void* d_ws, size_t ws_size,
                              hipStream_t stream) {
    const float* x     = (const float*)d_in[0];
    const float* cm    = (const float*)d_in[1];
    const float* gamma = (const float*)d_in[2];
    const float* beta  = (const float*)d_in[3];
    float* out = (float*)d_out;

    float* sbuf = (float*)d_ws;                                    // 1 MB
    f16*   cmP  = (f16*)(sbuf + (size_t)NN * EE);                  // 33.5 MB
    f16*   part = (f16*)((char*)cmP + (size_t)TSTEPS * 8192 * sizeof(f16)); // 16.8 MB

    hipLaunchKernelGGL(prep_kernel, dim3(NPACK + 32), dim3(256), 0, stream,
                       cm, cmP, x, sbuf);
    hipLaunchKernelGGL(gemm_kernel, dim3(16 * SPLITK), dim3(256), 0, stream,
                       x, sbuf, cmP, part);
    hipLaunchKernelGGL(reduce_ln_kernel, dim3(NN), dim3(256), 0, stream,
                       x, part, gamma, beta, out);
}

// Round 21
// 71.947 us; speedup vs baseline: 1.2925x; 1.2925x over previous
//
#include <hip/hip_runtime.h>
#include <hip/hip_fp16.h>
#include <cstdint>

#define BB 2
#define SS 512
#define EE 256
#define NN (BB*SS)           // 1024 rows
#define KTOT (EE*EE)         // 65536
#define SPLITK 32
#define KCHUNK (KTOT/SPLITK) // 2048
#define NSTEP 64             // 64 k-steps per chunk
#define TSTEPS (KTOT/32)     // 2048 packed 32-k blocks
#define LN_EPS 1e-3f

typedef _Float16 f16;
typedef _Float16 f16x8 __attribute__((ext_vector_type(8)));
typedef float    f32x4 __attribute__((ext_vector_type(4)));

#define NPREF 144            // wprefix blocks (triangular tiles), FIRST in grid
#define NPACK 512            // pack blocks: 4 cgroups x 128 kgroups

// ---------------- Kernel 1: FUSED wprefix (tile partials) + pack (LDS transpose).
// Blocks [0, NPREF): triangular weighted prefix partials -> ps.
// Blocks [NPREF, NPREF+NPACK): pack cm f32 -> cmP f16, coalesced both sides.
__global__ void prep_kernel(const float* __restrict__ cm, f16* __restrict__ cmP,
                            const float* __restrict__ x, float* __restrict__ ps) {
    __shared__ __align__(16) char smem[35072];
    const int bid = blockIdx.x;
    const int tid = threadIdx.x;
    const int wave = tid >> 6;
    const int lane = tid & 63;

    if (bid >= NPREF) {
        // ---- pack
        const int pb = bid - NPREF;
        const int cg = pb >> 7;           // 0..3
        const int kg = pb & 127;          // 0..127
        f16* lt = (f16*)smem;             // [64 slots][264] (pad 8)
        #pragma unroll
        for (int h = 0; h < 2; ++h) {
            #pragma unroll
            for (int i = 0; i < 8; ++i) {
                const int rl = i * 4 + wave;                   // 0..31
                const int row = cg * 64 + h * 32 + rl;
                const float* src = cm + (size_t)row * KTOT + kg * 512 + lane * 8;
                float4 lo = *(const float4*)(src);
                float4 hi = *(const float4*)(src + 4);
                f16x8 v = { (f16)lo.x, (f16)lo.y, (f16)lo.z, (f16)lo.w,
                            (f16)hi.x, (f16)hi.y, (f16)hi.z, (f16)hi.w };
                *(f16x8*)(lt + lane * 264 + rl * 8) = v;
            }
            __syncthreads();
            #pragma unroll
            for (int jj = 0; jj < 8; ++jj) {
                const int sl = jj * 8 + wave * 2 + (lane >> 5);  // slot 0..63
                const int cl = lane & 31;
                f16x8 v = *(const f16x8*)(lt + sl * 264 + cl * 8);
                const int t    = kg * 16 + (sl >> 2);
                const int koct = sl & 3;
                const int c    = cg * 64 + h * 32 + cl;
                *(f16x8*)(cmP + (size_t)t * 8192 + koct * 2048 + c * 8) = v;
            }
            __syncthreads();
        }
        return;
    }

    // ---- wprefix (one (b, eh, it, jt) tile per block)
    float (*xt)[128] = (float(*)[128])smem;            // 64 x 128 f32
    float* wl2 = (float*)(smem + 32768);               // 576 f32
    const int id = bid;                    // 0..143
    const int eh = id & 1;
    const int rest = id >> 1;
    const int b = rest / 36;
    const int r = rest % 36;
    int it = 0;
    while ((it + 1) * (it + 2) / 2 <= r) ++it;
    const int jt = r - it * (it + 1) / 2;

    for (int t = tid; t < 576; t += 256) {
        const int d = t - 64;
        wl2[t] = (d > 0) ? 1.0f / ((float)d * (float)d) : 0.0f;
    }
    const int jbase = jt * 64, ibase = it * 64;
    const float* xb = x + ((size_t)b * SS + jbase) * EE + eh * 128;
    #pragma unroll
    for (int p = 0; p < 8; ++p) {
        const int row = p * 8 + (tid >> 5);
        const int col = (tid & 31) * 4;
        *(float4*)&xt[row][col] = *(const float4*)(xb + (size_t)row * EE + col);
    }
    __syncthreads();

    const int g  = tid >> 5;
    const int ec = (tid & 31) * 4;
    const int irow = ibase + g * 8;
    float4 acc[8];
    #pragma unroll
    for (int m = 0; m < 8; ++m) acc[m] = (float4){0.f, 0.f, 0.f, 0.f};

    for (int jj = 0; jj < 64; ++jj) {
        const float4 xv = *(const float4*)&xt[jj][ec];
        const int wbase = irow - (jbase + jj) + 64;
        #pragma unroll
        for (int m = 0; m < 8; ++m) {
            const float w = wl2[wbase + m];
            acc[m].x += xv.x * w;
            acc[m].y += xv.y * w;
            acc[m].z += xv.z * w;
            acc[m].w += xv.w * w;
        }
    }

    float* base = ps + ((size_t)(((b * 2 + eh) * 8 + it) * 8 + jt)) * (64 * 128);
    #pragma unroll
    for (int m = 0; m < 8; ++m)
        *(float4*)(base + (size_t)(g * 8 + m) * 128 + ec) = acc[m];
}

// ---------------- Kernel 1b: fold j-tile partials -> s[n,e]
__global__ void reduce_s_kernel(const float* __restrict__ ps, float* __restrict__ s) {
    const int n = blockIdx.x;
    const int e = threadIdx.x;
    const int b = n >> 9, i = n & (SS - 1);
    const int it = i >> 6, il = i & 63;
    const int eh = e >> 7, ec = e & 127;
    const size_t tbase = (size_t)((b * 2 + eh) * 8 + it) * 8;
    float acc = 0.0f;
    for (int jt = 0; jt <= it; ++jt)
        acc += ps[(tbase + jt) * (64 * 128) + (size_t)il * 128 + ec];
    s[(size_t)n * EE + e] = acc;
}

// ---------------- Kernel 2: split-K MFMA GEMM — reg-direct B (R17 structure,
// SPLITK=32, 512 blocks), no sched_barriers (R20 A/B: neutral, simpler).
__launch_bounds__(256, 2)
__global__ void gemm_kernel(const float* __restrict__ x,
                            const float* __restrict__ sbuf,
                            const f16* __restrict__ cmP,
                            f16* __restrict__ part) {
    __shared__ __align__(16) f16 Ep[64 * 264];   // epilogue stage, 33.8 KB
    const int tid  = threadIdx.x;
    const int lane = tid & 63;
    const int wave = tid >> 6;       // col-quarter 0..3
    const int koct = lane >> 4;      // k-octet 0..3
    const int cl   = lane & 15;

    const int d = blockIdx.x;            // 0..511
    const int nblock = (d >> 3) & 15;
    const int chunk  = (d & 7) * 4 + (d >> 7);   // XCD-grouped chunks

    // ---- xf loads (8 global loads)
    f16x8 xf[4];
    #pragma unroll
    for (int rt = 0; rt < 4; ++rt) {
        const int r = nblock * 64 + rt * 16 + cl;
        const float* xr = x + (size_t)r * EE + chunk * 8;
        float4 xlo = *(const float4*)(xr);
        float4 xhi = *(const float4*)(xr + 4);
        xf[rt] = (f16x8){ (f16)xlo.x, (f16)xlo.y, (f16)xlo.z, (f16)xlo.w,
                          (f16)xhi.x, (f16)xhi.y, (f16)xhi.z, (f16)xhi.w };
    }
    // ---- svm m=0 loads (8 global loads)
    float4 p0[4][2];
    #pragma unroll
    for (int rt = 0; rt < 4; ++rt) {
        const int r = nblock * 64 + rt * 16 + cl;
        const float* sr = sbuf + (size_t)r * EE + koct * 8;
        p0[rt][0] = *(const float4*)(sr);
        p0[rt][1] = *(const float4*)(sr + 4);
    }

    // per-lane B base: chunk slice + koct slot + wave slice + col-low
    const char* bbase = (const char*)cmP + (size_t)chunk * (64 * 16384)
                      + koct * 4096 + wave * 1024 + cl * 16;
    // step v covers packed block t = ((v&7)<<3)|(v>>3)
    #define TOFF(v) ((size_t)((((v) & 7) << 3) | ((v) >> 3)) * 16384)
    #define LOADB(BUF, v) do {                                              \
        _Pragma("unroll")                                                   \
        for (int ct_ = 0; ct_ < 4; ++ct_)                                   \
            BUF[ct_] = *(const f16x8*)(bbase + TOFF(v) + ct_ * 256);        \
    } while (0)

    f16x8 b0[4], b1[4], b2[4], b3[4];
    LOADB(b0, 0); LOADB(b1, 1); LOADB(b2, 2);

    f32x4 acc[4][4];
    #pragma unroll
    for (int a = 0; a < 4; ++a)
        #pragma unroll
        for (int b = 0; b < 4; ++b) acc[a][b] = (f32x4){0.f, 0.f, 0.f, 0.f};

    f16x8 svm[4];
    #pragma unroll
    for (int rt = 0; rt < 4; ++rt)
        svm[rt] = (f16x8){ (f16)p0[rt][0].x, (f16)p0[rt][0].y,
                           (f16)p0[rt][0].z, (f16)p0[rt][0].w,
                           (f16)p0[rt][1].x, (f16)p0[rt][1].y,
                           (f16)p0[rt][1].z, (f16)p0[rt][1].w };

    float4 pnxt[4][2];

    // One step: uses buffer BU (holds B(v)), loads B(v+3) into BL.
    #define STEP(mm, aa, BU, BL) do {                                       \
        const int v_ = (mm) * 8 + (aa);                                     \
        if ((aa) == 6 && (mm) < 7) {                                        \
            _Pragma("unroll")                                               \
            for (int rt_ = 0; rt_ < 4; ++rt_) {                             \
                const int r_ = nblock * 64 + rt_ * 16 + cl;                 \
                const float* sr_ = sbuf + (size_t)r_ * EE + ((mm) + 1) * 32 \
                                 + koct * 8;                                \
                pnxt[rt_][0] = *(const float4*)(sr_);                       \
                pnxt[rt_][1] = *(const float4*)(sr_ + 4);                   \
            }                                                               \
        }                                                                   \
        f16x8 af_[4];                                                       \
        _Pragma("unroll")                                                   \
        for (int rt_ = 0; rt_ < 4; ++rt_) {                                 \
            const f16 xa_ = xf[rt_][(aa)];                                  \
            const f16x8 xa8_ = { xa_, xa_, xa_, xa_, xa_, xa_, xa_, xa_ };  \
            af_[rt_] = xa8_ * svm[rt_];                                     \
        }                                                                   \
        __builtin_amdgcn_s_setprio(1);                                      \
        _Pragma("unroll")                                                   \
        for (int ct_ = 0; ct_ < 4; ++ct_)                                   \
            _Pragma("unroll")                                               \
            for (int rt_ = 0; rt_ < 4; ++rt_)                               \
                acc[rt_][ct_] = __builtin_amdgcn_mfma_f32_16x16x32_f16(     \
                    af_[rt_], BU[ct_], acc[rt_][ct_], 0, 0, 0);             \
        __builtin_amdgcn_s_setprio(0);                                      \
        if (v_ + 3 < NSTEP) LOADB(BL, v_ + 3);                              \
        if ((aa) == 7 && (mm) < 7) {                                        \
            _Pragma("unroll")                                               \
            for (int rt_ = 0; rt_ < 4; ++rt_)                               \
                svm[rt_] = (f16x8){                                         \
                    (f16)pnxt[rt_][0].x, (f16)pnxt[rt_][0].y,               \
                    (f16)pnxt[rt_][0].z, (f16)pnxt[rt_][0].w,               \
                    (f16)pnxt[rt_][1].x, (f16)pnxt[rt_][1].y,               \
                    (f16)pnxt[rt_][1].z, (f16)pnxt[rt_][1].w };             \
        }                                                                   \
    } while (0)

    #pragma unroll
    for (int m = 0; m < 8; ++m) {
        STEP(m, 0, b0, b3);
        STEP(m, 1, b1, b0);
        STEP(m, 2, b2, b1);
        STEP(m, 3, b3, b2);
        STEP(m, 4, b0, b3);
        STEP(m, 5, b1, b0);
        STEP(m, 6, b2, b1);
        STEP(m, 7, b3, b2);
    }
    #undef STEP
    #undef LOADB
    #undef TOFF

    // ---- Epilogue: f16 via padded LDS stage, then contiguous row stores.
    __syncthreads();
    #pragma unroll
    for (int rt = 0; rt < 4; ++rt) {
        #pragma unroll
        for (int ct = 0; ct < 4; ++ct) {
            const int col = wave * 64 + ct * 16 + cl;
            #pragma unroll
            for (int q = 0; q < 4; ++q) {
                const int lr = rt * 16 + koct * 4 + q;
                Ep[lr * 264 + col] = (f16)acc[rt][ct][q];
            }
        }
    }
    __syncthreads();
    {
        const int lr  = tid >> 2;         // 0..63
        const int seg = tid & 3;          // 0..3 (64 cols each)
        f16* dst = part + ((size_t)chunk * NN + nblock * 64 + lr) * EE + seg * 64;
        const f16* srcE = Ep + lr * 264 + seg * 64;
        #pragma unroll
        for (int i = 0; i < 8; ++i)
            *(f16x8*)(dst + i * 8) = *(const f16x8*)(srcE + i * 8);
    }
}

// ---------------- Kernel 3: split-K reduce + residual + LayerNorm (f16 partials)
__global__ void reduce_ln_kernel(const float* __restrict__ x,
                                 const f16* __restrict__ part,
                                 const float* __restrict__ gamma,
                                 const float* __restrict__ beta,
                                 float* __restrict__ out) {
    const int n = blockIdx.x;
    const int c = threadIdx.x;
    const int lane = c & 63, wave = c >> 6;
    float y = x[(size_t)n * EE + c];
    #pragma unroll 8
    for (int ch = 0; ch < SPLITK; ++ch)
        y += (float)part[((size_t)ch * NN + n) * EE + c];

    float v = y;
    #pragma unroll
    for (int o = 32; o > 0; o >>= 1) v += __shfl_xor(v, o);
    __shared__ float red[8];
    if (lane == 0) red[wave] = v;
    __syncthreads();
    const float mean = (red[0] + red[1] + red[2] + red[3]) * (1.0f / EE);
    const float d = y - mean;
    float sq = d * d;
    #pragma unroll
    for (int o = 32; o > 0; o >>= 1) sq += __shfl_xor(sq, o);
    if (lane == 0) red[4 + wave] = sq;
    __syncthreads();
    const float var = (red[4] + red[5] + red[6] + red[7]) * (1.0f / EE);
    out[(size_t)n * EE + c] = d * rsqrtf(var + LN_EPS) * gamma[c] + beta[c];
}

extern "C" void kernel_launch(void* const* d_in, const int* in_sizes, int n_in,
                              void* d_out, int out_size, void* d_ws, size_t ws_size,
                              hipStream_t stream) {
    const float* x     = (const float*)d_in[0];
    const float* cm    = (const float*)d_in[1];
    const float* gamma = (const float*)d_in[2];
    const float* beta  = (const float*)d_in[3];
    float* out = (float*)d_out;

    float* sbuf = (float*)d_ws;                                    // 1 MB
    f16*   cmP  = (f16*)(sbuf + (size_t)NN * EE);                  // 33.5 MB
    f16*   part = (f16*)((char*)cmP + (size_t)TSTEPS * 8192 * sizeof(f16)); // 16.8 MB
    float* ps   = (float*)part;  // prefix partials (8.4 MB) alias part —
                                 // consumed by reduce_s before gemm writes part.

    hipLaunchKernelGGL(prep_kernel, dim3(NPREF + NPACK), dim3(256), 0, stream,
                       cm, cmP, x, ps);
    hipLaunchKernelGGL(reduce_s_kernel, dim3(NN), dim3(256), 0, stream, ps, sbuf);
    hipLaunchKernelGGL(gemm_kernel, dim3(16 * SPLITK), dim3(256), 0, stream,
                       x, sbuf, cmP, part);
    hipLaunchKernelGGL(reduce_ln_kernel, dim3(NN), dim3(256), 0, stream,
                       x, part, gamma, beta, out);
}

// Round 22
// 67.744 us; speedup vs baseline: 1.3726x; 1.0620x over previous
//
#include <hip/hip_runtime.h>
#include <hip/hip_fp16.h>
#include <cstdint>

#define BB 2
#define SS 512
#define EE 256
#define NN (BB*SS)           // 1024 rows
#define KTOT (EE*EE)         // 65536
#define SPLITK 32
#define KCHUNK (KTOT/SPLITK) // 2048
#define NSTEP 64             // 64 k-steps per chunk
#define TSTEPS (KTOT/32)     // 2048 packed 32-k blocks
#define LN_EPS 1e-3f

typedef _Float16 f16;
typedef _Float16 f16x8 __attribute__((ext_vector_type(8)));
typedef _Float16 f16x4 __attribute__((ext_vector_type(4)));
typedef float    f32x4 __attribute__((ext_vector_type(4)));

#define NPREF 144            // wprefix blocks (triangular tiles), FIRST in grid
#define NPACK 512            // pack blocks: 4 cgroups x 128 kgroups

// ---------------- Kernel 1: FUSED wprefix (tile partials) + pack (LDS transpose).
__global__ void prep_kernel(const float* __restrict__ cm, f16* __restrict__ cmP,
                            const float* __restrict__ x, float* __restrict__ ps) {
    __shared__ __align__(16) char smem[35072];
    const int bid = blockIdx.x;
    const int tid = threadIdx.x;
    const int wave = tid >> 6;
    const int lane = tid & 63;

    if (bid >= NPREF) {
        // ---- pack
        const int pb = bid - NPREF;
        const int cg = pb >> 7;           // 0..3
        const int kg = pb & 127;          // 0..127
        f16* lt = (f16*)smem;             // [64 slots][264] (pad 8)
        #pragma unroll
        for (int h = 0; h < 2; ++h) {
            #pragma unroll
            for (int i = 0; i < 8; ++i) {
                const int rl = i * 4 + wave;                   // 0..31
                const int row = cg * 64 + h * 32 + rl;
                const float* src = cm + (size_t)row * KTOT + kg * 512 + lane * 8;
                float4 lo = *(const float4*)(src);
                float4 hi = *(const float4*)(src + 4);
                f16x8 v = { (f16)lo.x, (f16)lo.y, (f16)lo.z, (f16)lo.w,
                            (f16)hi.x, (f16)hi.y, (f16)hi.z, (f16)hi.w };
                *(f16x8*)(lt + lane * 264 + rl * 8) = v;
            }
            __syncthreads();
            #pragma unroll
            for (int jj = 0; jj < 8; ++jj) {
                const int sl = jj * 8 + wave * 2 + (lane >> 5);  // slot 0..63
                const int cl = lane & 31;
                f16x8 v = *(const f16x8*)(lt + sl * 264 + cl * 8);
                const int t    = kg * 16 + (sl >> 2);
                const int koct = sl & 3;
                const int c    = cg * 64 + h * 32 + cl;
                *(f16x8*)(cmP + (size_t)t * 8192 + koct * 2048 + c * 8) = v;
            }
            __syncthreads();
        }
        return;
    }

    // ---- wprefix (one (b, eh, it, jt) tile per block)
    float (*xt)[128] = (float(*)[128])smem;            // 64 x 128 f32
    float* wl2 = (float*)(smem + 32768);               // 576 f32
    const int id = bid;                    // 0..143
    const int eh = id & 1;
    const int rest = id >> 1;
    const int b = rest / 36;
    const int r = rest % 36;
    int it = 0;
    while ((it + 1) * (it + 2) / 2 <= r) ++it;
    const int jt = r - it * (it + 1) / 2;

    for (int t = tid; t < 576; t += 256) {
        const int d = t - 64;
        wl2[t] = (d > 0) ? 1.0f / ((float)d * (float)d) : 0.0f;
    }
    const int jbase = jt * 64, ibase = it * 64;
    const float* xb = x + ((size_t)b * SS + jbase) * EE + eh * 128;
    #pragma unroll
    for (int p = 0; p < 8; ++p) {
        const int row = p * 8 + (tid >> 5);
        const int col = (tid & 31) * 4;
        *(float4*)&xt[row][col] = *(const float4*)(xb + (size_t)row * EE + col);
    }
    __syncthreads();

    const int g  = tid >> 5;
    const int ec = (tid & 31) * 4;
    const int irow = ibase + g * 8;
    float4 acc[8];
    #pragma unroll
    for (int m = 0; m < 8; ++m) acc[m] = (float4){0.f, 0.f, 0.f, 0.f};

    for (int jj = 0; jj < 64; ++jj) {
        const float4 xv = *(const float4*)&xt[jj][ec];
        const int wbase = irow - (jbase + jj) + 64;
        #pragma unroll
        for (int m = 0; m < 8; ++m) {
            const float w = wl2[wbase + m];
            acc[m].x += xv.x * w;
            acc[m].y += xv.y * w;
            acc[m].z += xv.z * w;
            acc[m].w += xv.w * w;
        }
    }

    float* base = ps + ((size_t)(((b * 2 + eh) * 8 + it) * 8 + jt)) * (64 * 128);
    #pragma unroll
    for (int m = 0; m < 8; ++m)
        *(float4*)(base + (size_t)(g * 8 + m) * 128 + ec) = acc[m];
}

// ---------------- Kernel 1b: fold j-tile partials -> s[n,e] as f16.
// (Identical rounding to the old gemm-side cvt — just moved here.)
__global__ void reduce_s_kernel(const float* __restrict__ ps, f16* __restrict__ s) {
    const int n = blockIdx.x;
    const int e = threadIdx.x;
    const int b = n >> 9, i = n & (SS - 1);
    const int it = i >> 6, il = i & 63;
    const int eh = e >> 7, ec = e & 127;
    const size_t tbase = (size_t)((b * 2 + eh) * 8 + it) * 8;
    float acc = 0.0f;
    for (int jt = 0; jt <= it; ++jt)
        acc += ps[(tbase + jt) * (64 * 128) + (size_t)il * 128 + ec];
    s[(size_t)n * EE + e] = (f16)acc;
}

// ---------------- Kernel 2: split-K MFMA GEMM — reg-direct B (R17/R21
// structure), f16 s-buffer (single f16x8 svm loads, no cvt VALU).
__launch_bounds__(256, 2)
__global__ void gemm_kernel(const float* __restrict__ x,
                            const f16* __restrict__ sbufH,
                            const f16* __restrict__ cmP,
                            f16* __restrict__ part) {
    __shared__ __align__(16) f16 Ep[64 * 264];   // epilogue stage, 33.8 KB
    const int tid  = threadIdx.x;
    const int lane = tid & 63;
    const int wave = tid >> 6;       // col-quarter 0..3
    const int koct = lane >> 4;      // k-octet 0..3
    const int cl   = lane & 15;

    const int d = blockIdx.x;            // 0..511
    const int nblock = (d >> 3) & 15;
    const int chunk  = (d & 7) * 4 + (d >> 7);   // XCD-grouped chunks

    // ---- xf loads (8 global loads)
    f16x8 xf[4];
    #pragma unroll
    for (int rt = 0; rt < 4; ++rt) {
        const int r = nblock * 64 + rt * 16 + cl;
        const float* xr = x + (size_t)r * EE + chunk * 8;
        float4 xlo = *(const float4*)(xr);
        float4 xhi = *(const float4*)(xr + 4);
        xf[rt] = (f16x8){ (f16)xlo.x, (f16)xlo.y, (f16)xlo.z, (f16)xlo.w,
                          (f16)xhi.x, (f16)xhi.y, (f16)xhi.z, (f16)xhi.w };
    }
    // ---- svm m=0 loads (4 f16x8 loads)
    f16x8 svm[4];
    #pragma unroll
    for (int rt = 0; rt < 4; ++rt) {
        const int r = nblock * 64 + rt * 16 + cl;
        svm[rt] = *(const f16x8*)(sbufH + (size_t)r * EE + koct * 8);
    }

    // per-lane B base: chunk slice + koct slot + wave slice + col-low
    const char* bbase = (const char*)cmP + (size_t)chunk * (64 * 16384)
                      + koct * 4096 + wave * 1024 + cl * 16;
    // step v covers packed block t = ((v&7)<<3)|(v>>3)
    #define TOFF(v) ((size_t)((((v) & 7) << 3) | ((v) >> 3)) * 16384)
    #define LOADB(BUF, v) do {                                              \
        _Pragma("unroll")                                                   \
        for (int ct_ = 0; ct_ < 4; ++ct_)                                   \
            BUF[ct_] = *(const f16x8*)(bbase + TOFF(v) + ct_ * 256);        \
    } while (0)

    f16x8 b0[4], b1[4], b2[4], b3[4];
    LOADB(b0, 0); LOADB(b1, 1); LOADB(b2, 2);

    f32x4 acc[4][4];
    #pragma unroll
    for (int a = 0; a < 4; ++a)
        #pragma unroll
        for (int b = 0; b < 4; ++b) acc[a][b] = (f32x4){0.f, 0.f, 0.f, 0.f};

    f16x8 pn[4];

    // One step: uses buffer BU (holds B(v)), loads B(v+3) into BL.
    #define STEP(mm, aa, BU, BL) do {                                       \
        const int v_ = (mm) * 8 + (aa);                                     \
        if ((aa) == 6 && (mm) < 7) {                                        \
            _Pragma("unroll")                                               \
            for (int rt_ = 0; rt_ < 4; ++rt_) {                             \
                const int r_ = nblock * 64 + rt_ * 16 + cl;                 \
                pn[rt_] = *(const f16x8*)(sbufH + (size_t)r_ * EE           \
                                          + ((mm) + 1) * 32 + koct * 8);    \
            }                                                               \
        }                                                                   \
        f16x8 af_[4];                                                       \
        _Pragma("unroll")                                                   \
        for (int rt_ = 0; rt_ < 4; ++rt_) {                                 \
            const f16 xa_ = xf[rt_][(aa)];                                  \
            const f16x8 xa8_ = { xa_, xa_, xa_, xa_, xa_, xa_, xa_, xa_ };  \
            af_[rt_] = xa8_ * svm[rt_];                                     \
        }                                                                   \
        __builtin_amdgcn_s_setprio(1);                                      \
        _Pragma("unroll")                                                   \
        for (int ct_ = 0; ct_ < 4; ++ct_)                                   \
            _Pragma("unroll")                                               \
            for (int rt_ = 0; rt_ < 4; ++rt_)                               \
                acc[rt_][ct_] = __builtin_amdgcn_mfma_f32_16x16x32_f16(     \
                    af_[rt_], BU[ct_], acc[rt_][ct_], 0, 0, 0);             \
        __builtin_amdgcn_s_setprio(0);                                      \
        if (v_ + 3 < NSTEP) LOADB(BL, v_ + 3);                              \
        if ((aa) == 7 && (mm) < 7) {                                        \
            _Pragma("unroll")                                               \
            for (int rt_ = 0; rt_ < 4; ++rt_) svm[rt_] = pn[rt_];           \
        }                                                                   \
    } while (0)

    #pragma unroll
    for (int m = 0; m < 8; ++m) {
        STEP(m, 0, b0, b3);
        STEP(m, 1, b1, b0);
        STEP(m, 2, b2, b1);
        STEP(m, 3, b3, b2);
        STEP(m, 4, b0, b3);
        STEP(m, 5, b1, b0);
        STEP(m, 6, b2, b1);
        STEP(m, 7, b3, b2);
    }
    #undef STEP
    #undef LOADB
    #undef TOFF

    // ---- Epilogue: f16 via padded LDS stage, then contiguous row stores.
    __syncthreads();
    #pragma unroll
    for (int rt = 0; rt < 4; ++rt) {
        #pragma unroll
        for (int ct = 0; ct < 4; ++ct) {
            const int col = wave * 64 + ct * 16 + cl;
            #pragma unroll
            for (int q = 0; q < 4; ++q) {
                const int lr = rt * 16 + koct * 4 + q;
                Ep[lr * 264 + col] = (f16)acc[rt][ct][q];
            }
        }
    }
    __syncthreads();
    {
        const int lr  = tid >> 2;         // 0..63
        const int seg = tid & 3;          // 0..3 (64 cols each)
        f16* dst = part + ((size_t)chunk * NN + nblock * 64 + lr) * EE + seg * 64;
        const f16* srcE = Ep + lr * 264 + seg * 64;
        #pragma unroll
        for (int i = 0; i < 8; ++i)
            *(f16x8*)(dst + i * 8) = *(const f16x8*)(srcE + i * 8);
    }
}

// ---------------- Kernel 3: split-K reduce + residual + LayerNorm.
// One n per wave (4 n per block); lane owns 4 c's -> f16x4 (8B) loads.
__global__ void reduce_ln_kernel(const float* __restrict__ x,
                                 const f16* __restrict__ part,
                                 const float* __restrict__ gamma,
                                 const float* __restrict__ beta,
                                 float* __restrict__ out) {
    const int wave = threadIdx.x >> 6;
    const int lane = threadIdx.x & 63;
    const int n = blockIdx.x * 4 + wave;
    const int c0 = lane * 4;

    float4 y = *(const float4*)(x + (size_t)n * EE + c0);
    #pragma unroll 8
    for (int ch = 0; ch < SPLITK; ++ch) {
        f16x4 p = *(const f16x4*)(part + ((size_t)ch * NN + n) * EE + c0);
        y.x += (float)p[0]; y.y += (float)p[1];
        y.z += (float)p[2]; y.w += (float)p[3];
    }

    float v = y.x + y.y + y.z + y.w;
    #pragma unroll
    for (int o = 32; o > 0; o >>= 1) v += __shfl_xor(v, o);
    const float mean = v * (1.0f / EE);
    const float dx = y.x - mean, dy = y.y - mean, dz = y.z - mean, dw = y.w - mean;
    float sq = dx * dx + dy * dy + dz * dz + dw * dw;
    #pragma unroll
    for (int o = 32; o > 0; o >>= 1) sq += __shfl_xor(sq, o);
    const float inv = rsqrtf(sq * (1.0f / EE) + LN_EPS);

    float4 g = *(const float4*)(gamma + c0);
    float4 bta = *(const float4*)(beta + c0);
    float4 o4 = { dx * inv * g.x + bta.x, dy * inv * g.y + bta.y,
                  dz * inv * g.z + bta.z, dw * inv * g.w + bta.w };
    *(float4*)(out + (size_t)n * EE + c0) = o4;
}

extern "C" void kernel_launch(void* const* d_in, const int* in_sizes, int n_in,
                              void* d_out, int out_size, void* d_ws, size_t ws_size,
                              hipStream_t stream) {
    const float* x     = (const float*)d_in[0];
    const float* cm    = (const float*)d_in[1];
    const float* gamma = (const float*)d_in[2];
    const float* beta  = (const float*)d_in[3];
    float* out = (float*)d_out;

    f16*   sbufH = (f16*)d_ws;                                     // 512 KB
    f16*   cmP   = (f16*)((char*)d_ws + (size_t)NN * EE * sizeof(f16)); // 33.5 MB
    f16*   part  = (f16*)((char*)cmP + (size_t)TSTEPS * 8192 * sizeof(f16)); // 16.8 MB
    float* ps    = (float*)part;  // prefix partials (8.4 MB) alias part —
                                  // consumed by reduce_s before gemm writes part.

    hipLaunchKernelGGL(prep_kernel, dim3(NPREF + NPACK), dim3(256), 0, stream,
                       cm, cmP, x, ps);
    hipLaunchKernelGGL(reduce_s_kernel, dim3(NN), dim3(256), 0, stream, ps, sbufH);
    hipLaunchKernelGGL(gemm_kernel, dim3(16 * SPLITK), dim3(256), 0, stream,
                       x, sbufH, cmP, part);
    hipLaunchKernelGGL(reduce_ln_kernel, dim3(NN / 4), dim3(256), 0, stream,
                       x, part, gamma, beta, out);
}